// Round 3
// baseline (427.148 us; speedup 1.0000x reference)
//
#include <hip/hip_runtime.h>
#include <hip/hip_bf16.h>

typedef __bf16 bf16x8 __attribute__((ext_vector_type(8)));
typedef float  f32x4  __attribute__((ext_vector_type(4)));

#define LOG2E 1.4426950408889634f
#define N4096 4096
#define NT 64

__device__ __forceinline__ void gl_lds16(const void* g, void* l) {
  __builtin_amdgcn_global_load_lds(
      (const __attribute__((address_space(1))) void*)g,
      (__attribute__((address_space(3))) void*)l, 16, 0, 0);
}

__device__ __forceinline__ void bar() {
  asm volatile("" ::: "memory");
  __builtin_amdgcn_s_barrier();
  asm volatile("" ::: "memory");
}

// ------- K1 (fused): blocks 0..4095 transpose x -> XFT bf16; blocks 4096..4351
//         compute z = xf @ proj_w + proj_b and sq = rowsum(z*z). Both read x only.
__global__ __launch_bounds__(256) void xpass_kernel(
    const float* __restrict__ x, const float* __restrict__ pw,
    const float* __restrict__ pb, float* __restrict__ z, float* __restrict__ sq,
    __hip_bfloat16* __restrict__ xft)
{
  __shared__ float t[64][65];
  int tid = threadIdx.x;
  if (blockIdx.x < 4096) {
    int bk = blockIdx.x & 63, bn = blockIdx.x >> 6;
    int c = tid & 63, r4 = tid >> 6;
    const float* src = x + (size_t)(bk * 64 + r4) * N4096 + bn * 64 + c;
#pragma unroll
    for (int p = 0; p < 16; ++p)
      t[r4 + p * 4][c] = src[(size_t)p * 4 * N4096];
    __syncthreads();
    __hip_bfloat16* dst = xft + (size_t)(bn * 64 + r4) * N4096 + bk * 64 + c;
#pragma unroll
    for (int p = 0; p < 16; ++p)
      dst[(size_t)p * 4 * N4096] = __float2bfloat16(t[c][r4 + p * 4]);
  } else {
    int wv = tid >> 6, lane = tid & 63;
    int row0 = (blockIdx.x - 4096) * 16 + wv * 4;
    const float* xr0 = x + (size_t)row0 * N4096;
    const float* xr1 = xr0 + N4096;
    const float* xr2 = xr1 + N4096;
    const float* xr3 = xr2 + N4096;
    float acc[4][16];
#pragma unroll
    for (int r = 0; r < 4; ++r)
#pragma unroll
      for (int l = 0; l < 16; ++l) acc[r][l] = 0.f;
    for (int k = lane; k < N4096; k += 64) {
      const float4* wp = (const float4*)(pw + (size_t)k * 16);
      float4 a = wp[0], b = wp[1], c = wp[2], d = wp[3];
      float w[16] = {a.x,a.y,a.z,a.w,b.x,b.y,b.z,b.w,c.x,c.y,c.z,c.w,d.x,d.y,d.z,d.w};
      float xv[4] = {xr0[k], xr1[k], xr2[k], xr3[k]};
#pragma unroll
      for (int r = 0; r < 4; ++r)
#pragma unroll
        for (int l = 0; l < 16; ++l) acc[r][l] += xv[r] * w[l];
    }
#pragma unroll
    for (int r = 0; r < 4; ++r)
#pragma unroll
      for (int l = 0; l < 16; ++l) {
        float v = acc[r][l];
#pragma unroll
        for (int off = 32; off; off >>= 1) v += __shfl_xor(v, off, 64);
        acc[r][l] = v;
      }
    if (lane == 0) {
#pragma unroll
      for (int r = 0; r < 4; ++r) {
        float s = 0.f;
#pragma unroll
        for (int l = 0; l < 16; ++l) {
          float zv = acc[r][l] + pb[l];
          z[(size_t)(row0 + r) * 16 + l] = zv;
          s += zv * zv;
        }
        sq[row0 + r] = s;
      }
    }
  }
}

// ------- K2: q_i = sum_j exp(-d2_ij); pi_i = sigmoid MLP; dvec = pi/q ---------
__global__ __launch_bounds__(256, 2) void piq_kernel(
    const float* __restrict__ z, const float* __restrict__ sq,
    const float* __restrict__ w1, const float* __restrict__ b1,
    const float* __restrict__ w2, const float* __restrict__ b2p,
    float* __restrict__ dvec)
{
  __shared__ float red[2][8][4];
  int tid = threadIdx.x;
  int i0 = blockIdx.x * 8;
  float zi[8][16], sqi[8];
#pragma unroll
  for (int r = 0; r < 8; ++r) {
    const float4* zp = (const float4*)(z + (size_t)(i0 + r) * 16);
    float4 a = zp[0], b = zp[1], c = zp[2], d = zp[3];
    zi[r][0]=a.x; zi[r][1]=a.y; zi[r][2]=a.z; zi[r][3]=a.w;
    zi[r][4]=b.x; zi[r][5]=b.y; zi[r][6]=b.z; zi[r][7]=b.w;
    zi[r][8]=c.x; zi[r][9]=c.y; zi[r][10]=c.z; zi[r][11]=c.w;
    zi[r][12]=d.x; zi[r][13]=d.y; zi[r][14]=d.z; zi[r][15]=d.w;
    sqi[r] = sq[i0 + r];
  }
  float accq[8], accp[8];
#pragma unroll
  for (int r = 0; r < 8; ++r) { accq[r] = 0.f; accp[r] = 0.f; }
  for (int jt = 0; jt < 16; ++jt) {
    int j = jt * 256 + tid;
    const float4* zp = (const float4*)(z + (size_t)j * 16);
    float4 z0 = zp[0], z1 = zp[1], z2 = zp[2], z3 = zp[3];
    float zj[16];
    zj[0]=z0.x; zj[1]=z0.y; zj[2]=z0.z; zj[3]=z0.w;
    zj[4]=z1.x; zj[5]=z1.y; zj[6]=z1.z; zj[7]=z1.w;
    zj[8]=z2.x; zj[9]=z2.y; zj[10]=z2.z; zj[11]=z2.w;
    zj[12]=z3.x; zj[13]=z3.y; zj[14]=z3.z; zj[15]=z3.w;
    float sqj = sq[j], b1j = b1[j], w2j = w2[j];
    float dz[8], dw[8];
#pragma unroll
    for (int r = 0; r < 8; ++r) { dz[r] = 0.f; dw[r] = 0.f; }
#pragma unroll
    for (int l = 0; l < 16; ++l) {
      float wl = w1[(size_t)l * N4096 + j];
      float zjl = zj[l];
#pragma unroll
      for (int r = 0; r < 8; ++r) { dz[r] += zi[r][l] * zjl; dw[r] += zi[r][l] * wl; }
    }
#pragma unroll
    for (int r = 0; r < 8; ++r) {
      accq[r] += exp2f(-LOG2E * (sqi[r] + sqj - 2.f * dz[r]));
      accp[r] += fmaxf(dw[r] + b1j, 0.f) * w2j;
    }
  }
  int lane = tid & 63, wv = tid >> 6;
#pragma unroll
  for (int r = 0; r < 8; ++r) {
    float a = accq[r], b = accp[r];
#pragma unroll
    for (int off = 32; off; off >>= 1) { a += __shfl_xor(a, off, 64); b += __shfl_xor(b, off, 64); }
    if (lane == 0) { red[0][r][wv] = a; red[1][r][wv] = b; }
  }
  __syncthreads();
  if (tid < 8) {
    float q = red[0][tid][0] + red[0][tid][1] + red[0][tid][2] + red[0][tid][3];
    float p = red[1][tid][0] + red[1][tid][1] + red[1][tid][2] + red[1][tid][3];
    float logit = p + b2p[0];
    float pi = 1.f / (1.f + exp2f(-LOG2E * logit));
    dvec[i0 + tid] = pi / q;
  }
}

// ------- K3: W[i][j] = bf16(exp(-d2_ij)*dvec[j]); rowscale = 4dt/(D+1e-5);
//         diag-fold: W[i][i] += (1-dt)/rowscale[i] so GEMM epilogue needs no x.
__global__ __launch_bounds__(256, 2) void wmat_kernel(
    const float* __restrict__ z, const float* __restrict__ sq,
    const float* __restrict__ dvec, const float* __restrict__ dtp,
    __hip_bfloat16* __restrict__ W, float* __restrict__ rowscale)
{
  __shared__ float red[8][4];
  int tid = threadIdx.x;
  int i0 = blockIdx.x * 8;
  float zi[8][16], sqi[8];
#pragma unroll
  for (int r = 0; r < 8; ++r) {
    const float4* zp = (const float4*)(z + (size_t)(i0 + r) * 16);
    float4 a = zp[0], b = zp[1], c = zp[2], d = zp[3];
    zi[r][0]=a.x; zi[r][1]=a.y; zi[r][2]=a.z; zi[r][3]=a.w;
    zi[r][4]=b.x; zi[r][5]=b.y; zi[r][6]=b.z; zi[r][7]=b.w;
    zi[r][8]=c.x; zi[r][9]=c.y; zi[r][10]=c.z; zi[r][11]=c.w;
    zi[r][12]=d.x; zi[r][13]=d.y; zi[r][14]=d.z; zi[r][15]=d.w;
    sqi[r] = sq[i0 + r];
  }
  float accD[8];
#pragma unroll
  for (int r = 0; r < 8; ++r) accD[r] = 0.f;
  for (int jt = 0; jt < 16; ++jt) {
    int j = jt * 256 + tid;
    const float4* zp = (const float4*)(z + (size_t)j * 16);
    float4 z0 = zp[0], z1 = zp[1], z2 = zp[2], z3 = zp[3];
    float zj[16];
    zj[0]=z0.x; zj[1]=z0.y; zj[2]=z0.z; zj[3]=z0.w;
    zj[4]=z1.x; zj[5]=z1.y; zj[6]=z1.z; zj[7]=z1.w;
    zj[8]=z2.x; zj[9]=z2.y; zj[10]=z2.z; zj[11]=z2.w;
    zj[12]=z3.x; zj[13]=z3.y; zj[14]=z3.z; zj[15]=z3.w;
    float sqj = sq[j], dvj = dvec[j];
    float dz[8];
#pragma unroll
    for (int r = 0; r < 8; ++r) dz[r] = 0.f;
#pragma unroll
    for (int l = 0; l < 16; ++l) {
      float zjl = zj[l];
#pragma unroll
      for (int r = 0; r < 8; ++r) dz[r] += zi[r][l] * zjl;
    }
#pragma unroll
    for (int r = 0; r < 8; ++r) {
      float w = exp2f(-LOG2E * (sqi[r] + sqj - 2.f * dz[r])) * dvj;
      W[(size_t)(i0 + r) * N4096 + j] = __float2bfloat16(w);
      accD[r] += w;
    }
  }
  int lane = tid & 63, wv = tid >> 6;
#pragma unroll
  for (int r = 0; r < 8; ++r) {
    float a = accD[r];
#pragma unroll
    for (int off = 32; off; off >>= 1) a += __shfl_xor(a, off, 64);
    if (lane == 0) red[r][wv] = a;
  }
  __syncthreads();
  if (tid < 8) {
    float dtv = dtp[0];
    float Dp = red[tid][0] + red[tid][1] + red[tid][2] + red[tid][3] + 1e-5f;
    rowscale[i0 + tid] = 4.f * dtv / Dp;
    int i = i0 + tid;
    // W'[i][i] = K~[i][i] + (1-dt)*(D+1e-5)/(4*dt)  (K~[i][i] = dvec[i])
    W[(size_t)i * N4096 + i] =
        __float2bfloat16(dvec[i] + (1.f - dtv) * Dp / (4.f * dtv));
  }
}

// ---------------- K4: out = rowscale[i] * (W' @ XFT^T) ------------------------
// 256x256 tile, BK=64, 8 waves (2Mx4N). Software-pipelined ds_reads:
// phase q loads af(q+1) (ping-pong regs); q3 does counted vmcnt then loads
// next tile's af(0) + all B-frags. MFMA never waits lgkmcnt(0) on own reads.
__global__ __launch_bounds__(512, 2) void gemm8_kernel(
    const __hip_bfloat16* __restrict__ Wm, const __hip_bfloat16* __restrict__ BT,
    const float* __restrict__ rowscale, float* __restrict__ out)
{
  extern __shared__ __bf16 S[];   // [2 bufs][A 16384 | B 16384] = 128 KB
  const int b0 = blockIdx.x;
  const int swz = (b0 & 7) * 32 + (b0 >> 3);   // 256 % 8 == 0: bijective
  const int tm = swz & 15, tn = swz >> 4;
  const int tid = threadIdx.x;
  const int lane = tid & 63;
  const int wv = tid >> 6;
  const int wr = wv >> 2, wc = wv & 3;         // 2 x 4 waves
  const int g = lane >> 4, rr = lane & 15;

  const int srow = tid >> 3;                   // 0..63 within a 64-row unit
  const int lslot = tid & 7;

  const __hip_bfloat16* Abase = Wm + (size_t)(tm * 256) * N4096;
  const __hip_bfloat16* Bbase = BT + (size_t)(tn * 256) * N4096;

  auto stageA = [&](int tk, int R0) {
    int r = R0 + srow;
    int gc = lslot ^ (r & 7);
    gl_lds16(Abase + (size_t)r * N4096 + tk * 64 + gc * 8,
             S + (size_t)(tk & 1) * 32768 + r * 64 + lslot * 8);
  };
  auto stageB = [&](int tk, int R0) {
    int r = R0 + srow;
    int gc = lslot ^ (r & 7);
    gl_lds16(Bbase + (size_t)r * N4096 + tk * 64 + gc * 8,
             S + (size_t)(tk & 1) * 32768 + 16384 + r * 64 + lslot * 8);
  };

  const __bf16* SA0 = S;
  const __bf16* SB0 = S + 16384;
  const __bf16* SA1 = S + 32768;
  const __bf16* SB1 = S + 49152;

  f32x4 acc[8][4];
#pragma unroll
  for (int i = 0; i < 8; ++i)
#pragma unroll
    for (int j = 0; j < 4; ++j) acc[i][j] = (f32x4){0.f, 0.f, 0.f, 0.f};

#define READA(dst, SAp, q)                                                     \
  { _Pragma("unroll") for (int mi2 = 0; mi2 < 2; ++mi2)                        \
      _Pragma("unroll") for (int kh = 0; kh < 2; ++kh) {                       \
        int row_ = wr * 128 + ((q) * 2 + mi2) * 16 + rr;                       \
        int slot_ = ((kh << 2) | g) ^ (rr & 7);                                \
        dst[mi2 * 2 + kh] = *(const bf16x8*)((SAp) + row_ * 64 + slot_ * 8);   \
      } }

#define READB(dst, SBp)                                                        \
  { _Pragma("unroll") for (int ni = 0; ni < 4; ++ni)                           \
      _Pragma("unroll") for (int kh = 0; kh < 2; ++kh) {                       \
        int row_ = wc * 64 + ni * 16 + rr;                                     \
        int slot_ = ((kh << 2) | g) ^ (rr & 7);                                \
        dst[ni][kh] = *(const bf16x8*)((SBp) + row_ * 64 + slot_ * 8);         \
      } }

#define MFMAQ(q, AF, BF)                                                       \
  { __builtin_amdgcn_s_setprio(1);                                            \
    _Pragma("unroll") for (int kh = 0; kh < 2; ++kh)                           \
      _Pragma("unroll") for (int mi2 = 0; mi2 < 2; ++mi2)                      \
        _Pragma("unroll") for (int ni = 0; ni < 4; ++ni)                       \
          acc[(q) * 2 + mi2][ni] = __builtin_amdgcn_mfma_f32_16x16x32_bf16(    \
              AF[mi2 * 2 + kh], BF[ni][kh], acc[(q) * 2 + mi2][ni], 0, 0, 0);  \
    __builtin_amdgcn_s_setprio(0); }

#define TILE(u, SAc, SAn, SBn, BFc, BFn)                                       \
  {                                                                            \
    if ((u) + 1 < NT) { stageA((u) + 1, 64); stageA((u) + 1, 192); }           \
    READA(afY, SAc, 1);                                                        \
    bar(); MFMAQ(0, afX, BFc); bar();                                          \
    if ((u) + 2 < NT) { stageB((u) + 2, 0); stageB((u) + 2, 64); }             \
    READA(afX, SAc, 2);                                                        \
    bar(); MFMAQ(1, afY, BFc); bar();                                          \
    if ((u) + 2 < NT) { stageB((u) + 2, 128); stageB((u) + 2, 192); }          \
    READA(afY, SAc, 3);                                                        \
    bar(); MFMAQ(2, afX, BFc); bar();                                          \
    if ((u) + 2 < NT) { stageA((u) + 2, 0); stageA((u) + 2, 128); }            \
    if ((u) + 1 < NT) {                                                        \
      if ((u) + 2 < NT) { asm volatile("s_waitcnt vmcnt(6)" ::: "memory"); }   \
      else              { asm volatile("s_waitcnt vmcnt(0)" ::: "memory"); }   \
      READA(afX, SAn, 0); READB(BFn, SBn);                                     \
    }                                                                          \
    bar(); MFMAQ(3, afY, BFc); bar();                                          \
  }

  // Prologue: tile0 full, tile1 partial (steady-state order), then preload frags
  stageA(0, 0); stageA(0, 64); stageA(0, 128); stageA(0, 192);
  stageB(0, 0); stageB(0, 64); stageB(0, 128); stageB(0, 192);
  stageB(1, 0); stageB(1, 64); stageB(1, 128); stageB(1, 192);
  stageA(1, 0); stageA(1, 128);
  asm volatile("s_waitcnt vmcnt(6)" ::: "memory");
  bar();

  bf16x8 bfP[4][2], bfN[4][2], afX[4], afY[4];
  READB(bfP, SB0);
  READA(afX, SA0, 0);

  for (int t = 0; t < NT; t += 2) {
    TILE(t,     SA0, SA1, SB1, bfP, bfN);
    TILE(t + 1, SA1, SA0, SB0, bfN, bfP);
  }
#undef TILE
#undef MFMAQ
#undef READB
#undef READA

#pragma unroll
  for (int mi = 0; mi < 8; ++mi) {
#pragma unroll
    for (int r4 = 0; r4 < 4; ++r4) {
      int row = tm * 256 + wr * 128 + mi * 16 + g * 4 + r4;
      float rs = rowscale[row];
      float* orow = out + (size_t)row * N4096;
#pragma unroll
      for (int ni = 0; ni < 4; ++ni) {
        int col = tn * 256 + wc * 64 + ni * 16 + rr;
        orow[col] = rs * acc[mi][ni][r4];
      }
    }
  }
}

extern "C" void kernel_launch(void* const* d_in, const int* in_sizes, int n_in,
                              void* d_out, int out_size, void* d_ws, size_t ws_size,
                              hipStream_t stream) {
  const float* x      = (const float*)d_in[0];
  const float* proj_w = (const float*)d_in[1];
  const float* proj_b = (const float*)d_in[2];
  const float* pi_w1  = (const float*)d_in[3];
  const float* pi_b1  = (const float*)d_in[4];
  const float* pi_w2  = (const float*)d_in[5];
  const float* pi_b2  = (const float*)d_in[6];
  const float* dt     = (const float*)d_in[7];
  float* out = (float*)d_out;

  char* ws = (char*)d_ws;
  const size_t MB = 1024 * 1024;
  __hip_bfloat16* W   = (__hip_bfloat16*)(ws);               // 32 MB
  __hip_bfloat16* XFT = (__hip_bfloat16*)(ws + 32 * MB);     // 32 MB
  float* z        = (float*)(ws + 64 * MB);                  // 256 KB
  float* sq       = (float*)(ws + 64 * MB + 256 * 1024);     // 16 KB
  float* dvec     = (float*)(ws + 64 * MB + 272 * 1024);     // 16 KB
  float* rowscale = (float*)(ws + 64 * MB + 288 * 1024);     // 16 KB

  (void)hipFuncSetAttribute((const void*)gemm8_kernel,
                            hipFuncAttributeMaxDynamicSharedMemorySize, 131072);

  xpass_kernel<<<4352, 256, 0, stream>>>(x, proj_w, proj_b, z, sq, XFT);
  piq_kernel<<<512, 256, 0, stream>>>(z, sq, pi_w1, pi_b1, pi_w2, pi_b2, dvec);
  wmat_kernel<<<512, 256, 0, stream>>>(z, sq, dvec, dt, W, rowscale);
  gemm8_kernel<<<256, 512, 131072, stream>>>(W, XFT, rowscale, out);
}

// Round 4
// 418.646 us; speedup vs baseline: 1.0203x; 1.0203x over previous
//
#include <hip/hip_runtime.h>
#include <hip/hip_bf16.h>

typedef __bf16 bf16x8 __attribute__((ext_vector_type(8)));
typedef float  f32x4  __attribute__((ext_vector_type(4)));

#define LOG2E 1.4426950408889634f
#define N4096 4096
#define NT 64

__device__ __forceinline__ void gl_lds16(const void* g, void* l) {
  __builtin_amdgcn_global_load_lds(
      (const __attribute__((address_space(1))) void*)g,
      (__attribute__((address_space(3))) void*)l, 16, 0, 0);
}

__device__ __forceinline__ void bar() {
  asm volatile("" ::: "memory");
  __builtin_amdgcn_s_barrier();
  asm volatile("" ::: "memory");
}

// ------- K1 (fused): blocks 0..255 = zproj + pi (16 rows each, 4/wave);
//         blocks 256..4351 = transpose x -> XFT bf16. zproj first => overlaps.
__global__ __launch_bounds__(256) void xpass_kernel(
    const float* __restrict__ x, const float* __restrict__ pw,
    const float* __restrict__ pb, const float* __restrict__ w1,
    const float* __restrict__ b1, const float* __restrict__ w2,
    const float* __restrict__ b2p,
    float* __restrict__ z, float* __restrict__ sq, float* __restrict__ piv,
    __hip_bfloat16* __restrict__ xft)
{
  __shared__ float t[64][65];
  int tid = threadIdx.x;
  if (blockIdx.x >= 256) {
    int bidx = blockIdx.x - 256;
    int bk = bidx & 63, bn = bidx >> 6;
    int c = tid & 63, r4 = tid >> 6;
    const float* src = x + (size_t)(bk * 64 + r4) * N4096 + bn * 64 + c;
#pragma unroll
    for (int p = 0; p < 16; ++p)
      t[r4 + p * 4][c] = src[(size_t)p * 4 * N4096];
    __syncthreads();
    __hip_bfloat16* dst = xft + (size_t)(bn * 64 + r4) * N4096 + bk * 64 + c;
#pragma unroll
    for (int p = 0; p < 16; ++p)
      dst[(size_t)p * 4 * N4096] = __float2bfloat16(t[c][r4 + p * 4]);
  } else {
    int wv = tid >> 6, lane = tid & 63;
    int row0 = blockIdx.x * 16 + wv * 4;
    const float* xr0 = x + (size_t)row0 * N4096;
    const float* xr1 = xr0 + N4096;
    const float* xr2 = xr1 + N4096;
    const float* xr3 = xr2 + N4096;
    float acc[4][16];
#pragma unroll
    for (int r = 0; r < 4; ++r)
#pragma unroll
      for (int l = 0; l < 16; ++l) acc[r][l] = 0.f;
    for (int k = lane; k < N4096; k += 64) {
      const float4* wp = (const float4*)(pw + (size_t)k * 16);
      float4 a = wp[0], b = wp[1], c = wp[2], d = wp[3];
      float w[16] = {a.x,a.y,a.z,a.w,b.x,b.y,b.z,b.w,c.x,c.y,c.z,c.w,d.x,d.y,d.z,d.w};
      float xv[4] = {xr0[k], xr1[k], xr2[k], xr3[k]};
#pragma unroll
      for (int r = 0; r < 4; ++r)
#pragma unroll
        for (int l = 0; l < 16; ++l) acc[r][l] += xv[r] * w[l];
    }
    // butterfly: all lanes end with the full sum
#pragma unroll
    for (int r = 0; r < 4; ++r)
#pragma unroll
      for (int l = 0; l < 16; ++l) {
        float v = acc[r][l];
#pragma unroll
        for (int off = 32; off; off >>= 1) v += __shfl_xor(v, off, 64);
        acc[r][l] = v + pb[l];          // z value, on every lane
      }
    if (lane == 0) {
#pragma unroll
      for (int r = 0; r < 4; ++r) {
        float s = 0.f;
#pragma unroll
        for (int l = 0; l < 16; ++l) {
          z[(size_t)(row0 + r) * 16 + l] = acc[r][l];
          s += acc[r][l] * acc[r][l];
        }
        sq[row0 + r] = s;
      }
    }
    // pi_r = sigmoid( sum_j relu(z_r . w1[:,j] + b1_j) * w2_j + b2 )
    float accp[4] = {0.f, 0.f, 0.f, 0.f};
    for (int j = lane; j < N4096; j += 64) {
      float b1j = b1[j], w2j = w2[j];
      float t0 = b1j, t1 = b1j, t2 = b1j, t3 = b1j;
#pragma unroll
      for (int l = 0; l < 16; ++l) {
        float wl = w1[(size_t)l * N4096 + j];
        t0 += acc[0][l] * wl; t1 += acc[1][l] * wl;
        t2 += acc[2][l] * wl; t3 += acc[3][l] * wl;
      }
      accp[0] += fmaxf(t0, 0.f) * w2j;
      accp[1] += fmaxf(t1, 0.f) * w2j;
      accp[2] += fmaxf(t2, 0.f) * w2j;
      accp[3] += fmaxf(t3, 0.f) * w2j;
    }
#pragma unroll
    for (int r = 0; r < 4; ++r) {
      float v = accp[r];
#pragma unroll
      for (int off = 32; off; off >>= 1) v += __shfl_xor(v, off, 64);
      if (lane == 0) {
        float logit = v + b2p[0];
        piv[row0 + r] = 1.f / (1.f + exp2f(-LOG2E * logit));
      }
    }
  }
}

// ------- K2: q_i = sum_j exp(-d2_ij); dvec_i = piv_i / q_i --------------------
__global__ __launch_bounds__(512, 2) void qpass_kernel(
    const float* __restrict__ z, const float* __restrict__ sq,
    const float* __restrict__ piv, float* __restrict__ dvec)
{
  __shared__ float red[4][8];
  int tid = threadIdx.x;
  int i0 = blockIdx.x * 4;
  float zi[4][16], sqi[4];
#pragma unroll
  for (int r = 0; r < 4; ++r) {
    const float4* zp = (const float4*)(z + (size_t)(i0 + r) * 16);
    float4 a = zp[0], b = zp[1], c = zp[2], d = zp[3];
    zi[r][0]=a.x; zi[r][1]=a.y; zi[r][2]=a.z; zi[r][3]=a.w;
    zi[r][4]=b.x; zi[r][5]=b.y; zi[r][6]=b.z; zi[r][7]=b.w;
    zi[r][8]=c.x; zi[r][9]=c.y; zi[r][10]=c.z; zi[r][11]=c.w;
    zi[r][12]=d.x; zi[r][13]=d.y; zi[r][14]=d.z; zi[r][15]=d.w;
    sqi[r] = sq[i0 + r];
  }
  float accq[4] = {0.f, 0.f, 0.f, 0.f};
  for (int jt = 0; jt < 8; ++jt) {
    int j = jt * 512 + tid;
    const float4* zp = (const float4*)(z + (size_t)j * 16);
    float4 z0 = zp[0], z1 = zp[1], z2 = zp[2], z3 = zp[3];
    float zj[16];
    zj[0]=z0.x; zj[1]=z0.y; zj[2]=z0.z; zj[3]=z0.w;
    zj[4]=z1.x; zj[5]=z1.y; zj[6]=z1.z; zj[7]=z1.w;
    zj[8]=z2.x; zj[9]=z2.y; zj[10]=z2.z; zj[11]=z2.w;
    zj[12]=z3.x; zj[13]=z3.y; zj[14]=z3.z; zj[15]=z3.w;
    float sqj = sq[j];
    float dz[4] = {0.f, 0.f, 0.f, 0.f};
#pragma unroll
    for (int l = 0; l < 16; ++l) {
      float zjl = zj[l];
#pragma unroll
      for (int r = 0; r < 4; ++r) dz[r] += zi[r][l] * zjl;
    }
#pragma unroll
    for (int r = 0; r < 4; ++r)
      accq[r] += exp2f(-LOG2E * (sqi[r] + sqj - 2.f * dz[r]));
  }
  int lane = tid & 63, wv = tid >> 6;
#pragma unroll
  for (int r = 0; r < 4; ++r) {
    float a = accq[r];
#pragma unroll
    for (int off = 32; off; off >>= 1) a += __shfl_xor(a, off, 64);
    if (lane == 0) red[r][wv] = a;
  }
  __syncthreads();
  if (tid < 4) {
    float q = 0.f;
#pragma unroll
    for (int w = 0; w < 8; ++w) q += red[tid][w];
    dvec[i0 + tid] = piv[i0 + tid] / q;
  }
}

// ------- K3: W[i][j] = bf16(exp(-d2_ij)*dvec[j]); rowscale = 4dt/(D+1e-5);
//         diag-fold: W[i][i] = dvec[i] + (1-dt)(D+1e-5)/(4dt) (x-term in GEMM).
__global__ __launch_bounds__(512, 2) void wmat_kernel(
    const float* __restrict__ z, const float* __restrict__ sq,
    const float* __restrict__ dvec, const float* __restrict__ dtp,
    __hip_bfloat16* __restrict__ W, float* __restrict__ rowscale)
{
  __shared__ float red[4][8];
  int tid = threadIdx.x;
  int i0 = blockIdx.x * 4;
  float zi[4][16], sqi[4];
#pragma unroll
  for (int r = 0; r < 4; ++r) {
    const float4* zp = (const float4*)(z + (size_t)(i0 + r) * 16);
    float4 a = zp[0], b = zp[1], c = zp[2], d = zp[3];
    zi[r][0]=a.x; zi[r][1]=a.y; zi[r][2]=a.z; zi[r][3]=a.w;
    zi[r][4]=b.x; zi[r][5]=b.y; zi[r][6]=b.z; zi[r][7]=b.w;
    zi[r][8]=c.x; zi[r][9]=c.y; zi[r][10]=c.z; zi[r][11]=c.w;
    zi[r][12]=d.x; zi[r][13]=d.y; zi[r][14]=d.z; zi[r][15]=d.w;
    sqi[r] = sq[i0 + r];
  }
  float accD[4] = {0.f, 0.f, 0.f, 0.f};
  for (int jt = 0; jt < 8; ++jt) {
    int j = jt * 512 + tid;
    const float4* zp = (const float4*)(z + (size_t)j * 16);
    float4 z0 = zp[0], z1 = zp[1], z2 = zp[2], z3 = zp[3];
    float zj[16];
    zj[0]=z0.x; zj[1]=z0.y; zj[2]=z0.z; zj[3]=z0.w;
    zj[4]=z1.x; zj[5]=z1.y; zj[6]=z1.z; zj[7]=z1.w;
    zj[8]=z2.x; zj[9]=z2.y; zj[10]=z2.z; zj[11]=z2.w;
    zj[12]=z3.x; zj[13]=z3.y; zj[14]=z3.z; zj[15]=z3.w;
    float sqj = sq[j], dvj = dvec[j];
    float dz[4] = {0.f, 0.f, 0.f, 0.f};
#pragma unroll
    for (int l = 0; l < 16; ++l) {
      float zjl = zj[l];
#pragma unroll
      for (int r = 0; r < 4; ++r) dz[r] += zi[r][l] * zjl;
    }
#pragma unroll
    for (int r = 0; r < 4; ++r) {
      float w = exp2f(-LOG2E * (sqi[r] + sqj - 2.f * dz[r])) * dvj;
      W[(size_t)(i0 + r) * N4096 + j] = __float2bfloat16(w);
      accD[r] += w;
    }
  }
  int lane = tid & 63, wv = tid >> 6;
#pragma unroll
  for (int r = 0; r < 4; ++r) {
    float a = accD[r];
#pragma unroll
    for (int off = 32; off; off >>= 1) a += __shfl_xor(a, off, 64);
    if (lane == 0) red[r][wv] = a;
  }
  __syncthreads();
  if (tid < 4) {
    float dtv = dtp[0];
    float Dp = 0.f;
#pragma unroll
    for (int w = 0; w < 8; ++w) Dp += red[tid][w];
    Dp += 1e-5f;
    int i = i0 + tid;
    rowscale[i] = 4.f * dtv / Dp;
    W[(size_t)i * N4096 + i] =
        __float2bfloat16(dvec[i] + (1.f - dtv) * Dp / (4.f * dtv));
  }
}

// ---------------- K4: out = rowscale[i] * (W' @ XFT^T) ------------------------
// EXACT round-2 schedule (compiler-scheduled in-phase ds_reads): 256x256 tile,
// BK=64, 8 waves (2Mx4N), counted vmcnt(6), raw s_barrier, setprio, XOR swizzle.
__global__ __launch_bounds__(512, 2) void gemm8_kernel(
    const __hip_bfloat16* __restrict__ Wm, const __hip_bfloat16* __restrict__ BT,
    const float* __restrict__ rowscale, float* __restrict__ out)
{
  extern __shared__ __bf16 S[];   // [2 bufs][A 16384 | B 16384] = 128 KB
  const int b0 = blockIdx.x;
  const int swz = (b0 & 7) * 32 + (b0 >> 3);   // 256 % 8 == 0: bijective
  const int tm = swz & 15, tn = swz >> 4;
  const int tid = threadIdx.x;
  const int lane = tid & 63;
  const int wv = tid >> 6;
  const int wr = wv >> 2, wc = wv & 3;         // 2 x 4 waves
  const int g = lane >> 4, rr = lane & 15;

  const int srow = tid >> 3;                   // 0..63 within a 64-row unit
  const int lslot = tid & 7;                   // linear LDS slot (8 bf16 each)

  const __hip_bfloat16* Abase = Wm + (size_t)(tm * 256) * N4096;
  const __hip_bfloat16* Bbase = BT + (size_t)(tn * 256) * N4096;

  auto stageA = [&](int tk, int R0) {
    int r = R0 + srow;
    int gc = lslot ^ (r & 7);                  // pre-swizzled global source
    gl_lds16(Abase + (size_t)r * N4096 + tk * 64 + gc * 8,
             S + (size_t)(tk & 1) * 32768 + r * 64 + lslot * 8);
  };
  auto stageB = [&](int tk, int R0) {
    int r = R0 + srow;
    int gc = lslot ^ (r & 7);
    gl_lds16(Bbase + (size_t)r * N4096 + tk * 64 + gc * 8,
             S + (size_t)(tk & 1) * 32768 + 16384 + r * 64 + lslot * 8);
  };

  f32x4 acc[8][4];
#pragma unroll
  for (int i = 0; i < 8; ++i)
#pragma unroll
    for (int j = 0; j < 4; ++j) acc[i][j] = (f32x4){0.f, 0.f, 0.f, 0.f};

  // Prologue: tile0 full (8 units), tile1 partial (6 units, steady-state order)
  stageA(0, 0); stageA(0, 64); stageA(0, 128); stageA(0, 192);
  stageB(0, 0); stageB(0, 64); stageB(0, 128); stageB(0, 192);
  stageB(1, 0); stageB(1, 64); stageB(1, 128); stageB(1, 192);
  stageA(1, 0); stageA(1, 128);
  asm volatile("s_waitcnt vmcnt(6)" ::: "memory");
  bar();

  for (int t = 0; t < NT; ++t) {
    const __bf16* sAb = S + (size_t)(t & 1) * 32768;
    const __bf16* sBb = sAb + 16384;
    bf16x8 bfrag[4][2];

#define APHASE(q)                                                              \
    {                                                                          \
      bf16x8 af[2][2];                                                         \
      _Pragma("unroll")                                                        \
      for (int mi2 = 0; mi2 < 2; ++mi2) {                                      \
        _Pragma("unroll")                                                      \
        for (int kh = 0; kh < 2; ++kh) {                                       \
          int row_ = wr * 128 + ((q) * 2 + mi2) * 16 + rr;                     \
          int slot_ = ((kh << 2) | g) ^ (rr & 7);                              \
          af[mi2][kh] = *(const bf16x8*)(sAb + row_ * 64 + slot_ * 8);         \
        }                                                                      \
      }                                                                        \
      bar();                                                                   \
      __builtin_amdgcn_s_setprio(1);                                          \
      _Pragma("unroll")                                                        \
      for (int kh = 0; kh < 2; ++kh)                                           \
        _Pragma("unroll")                                                      \
        for (int mi2 = 0; mi2 < 2; ++mi2)                                      \
          _Pragma("unroll")                                                    \
          for (int ni = 0; ni < 4; ++ni)                                       \
            acc[(q) * 2 + mi2][ni] = __builtin_amdgcn_mfma_f32_16x16x32_bf16(  \
                af[mi2][kh], bfrag[ni][kh], acc[(q) * 2 + mi2][ni], 0, 0, 0);  \
      __builtin_amdgcn_s_setprio(0);                                          \
    }

    // ---- phase 0: stage tile t+1's last two A units; read B + A-quadrant 0
    if (t + 1 < NT) { stageA(t + 1, 64); stageA(t + 1, 192); }
#pragma unroll
    for (int ni = 0; ni < 4; ++ni)
#pragma unroll
      for (int kh = 0; kh < 2; ++kh) {
        int row_ = wc * 64 + ni * 16 + rr;
        int slot_ = ((kh << 2) | g) ^ (rr & 7);
        bfrag[ni][kh] = *(const bf16x8*)(sBb + row_ * 64 + slot_ * 8);
      }
    APHASE(0);
    bar();
    // ---- phase 1: B of tile t is dead -> stage tile t+2's B half 0
    if (t + 2 < NT) { stageB(t + 2, 0); stageB(t + 2, 64); }
    APHASE(1);
    bar();
    // ---- phase 2: stage tile t+2's B half 1
    if (t + 2 < NT) { stageB(t + 2, 128); stageB(t + 2, 192); }
    APHASE(2);
    bar();
    // ---- phase 3: A units 0,128 of tile t dead after quadrants 0-1 -> stage
    if (t + 2 < NT) { stageA(t + 2, 0); stageA(t + 2, 128); }
    APHASE(3);
    // ---- tile boundary: counted wait (tile t+1 staged; t+2's 6 stay in flight)
    if (t + 2 < NT)      { asm volatile("s_waitcnt vmcnt(6)" ::: "memory"); }
    else if (t + 1 < NT) { asm volatile("s_waitcnt vmcnt(0)" ::: "memory"); }
    bar();
#undef APHASE
  }

#pragma unroll
  for (int mi = 0; mi < 8; ++mi) {
#pragma unroll
    for (int r4 = 0; r4 < 4; ++r4) {
      int row = tm * 256 + wr * 128 + mi * 16 + g * 4 + r4;
      float rs = rowscale[row];
      float* orow = out + (size_t)row * N4096;
#pragma unroll
      for (int ni = 0; ni < 4; ++ni) {
        int col = tn * 256 + wc * 64 + ni * 16 + rr;
        orow[col] = rs * acc[mi][ni][r4];
      }
    }
  }
}

extern "C" void kernel_launch(void* const* d_in, const int* in_sizes, int n_in,
                              void* d_out, int out_size, void* d_ws, size_t ws_size,
                              hipStream_t stream) {
  const float* x      = (const float*)d_in[0];
  const float* proj_w = (const float*)d_in[1];
  const float* proj_b = (const float*)d_in[2];
  const float* pi_w1  = (const float*)d_in[3];
  const float* pi_b1  = (const float*)d_in[4];
  const float* pi_w2  = (const float*)d_in[5];
  const float* pi_b2  = (const float*)d_in[6];
  const float* dt     = (const float*)d_in[7];
  float* out = (float*)d_out;

  char* ws = (char*)d_ws;
  const size_t MB = 1024 * 1024;
  __hip_bfloat16* W   = (__hip_bfloat16*)(ws);               // 32 MB
  __hip_bfloat16* XFT = (__hip_bfloat16*)(ws + 32 * MB);     // 32 MB
  float* z        = (float*)(ws + 64 * MB);                  // 256 KB
  float* sq       = (float*)(ws + 64 * MB + 256 * 1024);     // 16 KB
  float* piv      = (float*)(ws + 64 * MB + 272 * 1024);     // 16 KB
  float* dvec     = (float*)(ws + 64 * MB + 288 * 1024);     // 16 KB
  float* rowscale = (float*)(ws + 64 * MB + 304 * 1024);     // 16 KB

  (void)hipFuncSetAttribute((const void*)gemm8_kernel,
                            hipFuncAttributeMaxDynamicSharedMemorySize, 131072);

  xpass_kernel<<<4352, 256, 0, stream>>>(x, proj_w, proj_b, pi_w1, pi_b1,
                                         pi_w2, pi_b2, z, sq, piv, XFT);
  qpass_kernel<<<1024, 512, 0, stream>>>(z, sq, piv, dvec);
  wmat_kernel<<<1024, 512, 0, stream>>>(z, sq, dvec, dt, W, rowscale);
  gemm8_kernel<<<256, 512, 131072, stream>>>(W, XFT, rowscale, out);
}

// Round 5
// 221.964 us; speedup vs baseline: 1.9244x; 1.8861x over previous
//
#include <hip/hip_runtime.h>
#include <hip/hip_bf16.h>

typedef __bf16 bf16x8 __attribute__((ext_vector_type(8)));
typedef float  f32x4  __attribute__((ext_vector_type(4)));

#define LOG2E 1.4426950408889634f
#define N4096 4096
#define NT 64

__device__ __forceinline__ void gl_lds16(const void* g, void* l) {
  __builtin_amdgcn_global_load_lds(
      (const __attribute__((address_space(1))) void*)g,
      (__attribute__((address_space(3))) void*)l, 16, 0, 0);
}

__device__ __forceinline__ void bar() {
  asm volatile("" ::: "memory");
  __builtin_amdgcn_s_barrier();
  asm volatile("" ::: "memory");
}

// ------- K1: blocks 0..511 = zproj (2 rows/wave, named f32x4 accs, no arrays)
//         + zero qacc/piacc; blocks 512..4607 = transpose x -> XFT bf16.
__global__ __launch_bounds__(256) void xpass_kernel(
    const float* __restrict__ x, const float* __restrict__ pw,
    const float* __restrict__ pb,
    float* __restrict__ z, float* __restrict__ sq,
    float* __restrict__ qacc, float* __restrict__ piacc,
    __hip_bfloat16* __restrict__ xft)
{
  __shared__ float t[64][65];
  int tid = threadIdx.x;
  if (blockIdx.x >= 512) {
    int bidx = blockIdx.x - 512;
    int bk = bidx & 63, bn = bidx >> 6;
    int c = tid & 63, r4 = tid >> 6;
    const float* src = x + (size_t)(bk * 64 + r4) * N4096 + bn * 64 + c;
#pragma unroll
    for (int p = 0; p < 16; ++p)
      t[r4 + p * 4][c] = src[(size_t)p * 4 * N4096];
    __syncthreads();
    __hip_bfloat16* dst = xft + (size_t)(bn * 64 + r4) * N4096 + bk * 64 + c;
#pragma unroll
    for (int p = 0; p < 16; ++p)
      dst[(size_t)p * 4 * N4096] = __float2bfloat16(t[c][r4 + p * 4]);
  } else {
    // zero the atomic accumulators (4096 each; 8 per block)
    if (tid < 8) {
      int idx = blockIdx.x * 8 + tid;
      qacc[idx] = 0.f;
      piacc[idx] = 0.f;
    }
    int wv = tid >> 6, lane = tid & 63;
    int row0 = blockIdx.x * 8 + wv * 2;
    const float* xr0 = x + (size_t)row0 * N4096;
    const float* xr1 = xr0 + N4096;
    f32x4 a0 = {0,0,0,0}, b0 = {0,0,0,0}, c0 = {0,0,0,0}, d0 = {0,0,0,0};
    f32x4 a1 = {0,0,0,0}, b1 = {0,0,0,0}, c1 = {0,0,0,0}, d1 = {0,0,0,0};
    for (int k = lane; k < N4096; k += 64) {
      const f32x4* wp = (const f32x4*)(pw + (size_t)k * 16);
      f32x4 wa = wp[0], wb = wp[1], wc = wp[2], wd = wp[3];
      float x0 = xr0[k], x1 = xr1[k];
      a0 += wa * x0; b0 += wb * x0; c0 += wc * x0; d0 += wd * x0;
      a1 += wa * x1; b1 += wb * x1; c1 += wc * x1; d1 += wd * x1;
    }
#define RED4(v)                                                                \
    { _Pragma("unroll") for (int c_ = 0; c_ < 4; ++c_) {                       \
        float s_ = v[c_];                                                      \
        _Pragma("unroll") for (int o_ = 32; o_; o_ >>= 1)                      \
          s_ += __shfl_xor(s_, o_, 64);                                        \
        v[c_] = s_; } }
    RED4(a0); RED4(b0); RED4(c0); RED4(d0);
    RED4(a1); RED4(b1); RED4(c1); RED4(d1);
#undef RED4
    const f32x4* pbq = (const f32x4*)pb;
    f32x4 pa = pbq[0], pbv = pbq[1], pc = pbq[2], pd = pbq[3];
    a0 += pa; b0 += pbv; c0 += pc; d0 += pd;
    a1 += pa; b1 += pbv; c1 += pc; d1 += pd;
    if (lane == 0) {
      f32x4* z0 = (f32x4*)(z + (size_t)row0 * 16);
      z0[0] = a0; z0[1] = b0; z0[2] = c0; z0[3] = d0;
      z0[4] = a1; z0[5] = b1; z0[6] = c1; z0[7] = d1;
      f32x4 s0 = a0*a0 + b0*b0 + c0*c0 + d0*d0;
      f32x4 s1 = a1*a1 + b1*b1 + c1*c1 + d1*d1;
      sq[row0]     = s0[0] + s0[1] + s0[2] + s0[3];
      sq[row0 + 1] = s1[0] + s1[1] + s1[2] + s1[3];
    }
  }
}

// ------- K2: qpi — thread owns one i-row; j-chunk (128) staged in LDS.
//         accq/accpi partials via atomicAdd (32 adds per address total).
__global__ __launch_bounds__(256) void qpi_kernel(
    const float* __restrict__ z, const float* __restrict__ sq,
    const float* __restrict__ w1, const float* __restrict__ b1,
    const float* __restrict__ w2,
    float* __restrict__ qacc, float* __restrict__ piacc)
{
  __shared__ float zjl[128 * 16];   // 8 KB  [jj][16]
  __shared__ float w1t[128 * 16];   // 8 KB  [jj][16] (transposed w1 chunk)
  __shared__ float meta[128 * 4];   // 2 KB  (sqj, b1j, w2j, 0)
  int tid = threadIdx.x;
  int it = blockIdx.x >> 5, jc = blockIdx.x & 31;
  int i  = it * 256 + tid;
  int j0 = jc * 128;
  {
    f32x4* zd = (f32x4*)zjl;
    const f32x4* zs = (const f32x4*)(z + (size_t)j0 * 16);
    zd[tid] = zs[tid];
    zd[tid + 256] = zs[tid + 256];
#pragma unroll
    for (int k = 0; k < 8; ++k) {
      int idx = tid + k * 256;
      int jj = idx >> 4, l = idx & 15;
      w1t[jj * 16 + l] = w1[(size_t)l * N4096 + j0 + jj];
    }
    if (tid < 128) {
      meta[tid * 4 + 0] = sq[j0 + tid];
      meta[tid * 4 + 1] = b1[j0 + tid];
      meta[tid * 4 + 2] = w2[j0 + tid];
      meta[tid * 4 + 3] = 0.f;
    }
  }
  __syncthreads();
  const f32x4* ziq = (const f32x4*)(z + (size_t)i * 16);
  f32x4 zi0 = ziq[0], zi1 = ziq[1], zi2 = ziq[2], zi3 = ziq[3];
  float sqi = sq[i];
  float accq = 0.f, accp = 0.f;
  for (int jj = 0; jj < 128; ++jj) {
    const f32x4* zq = (const f32x4*)(zjl + jj * 16);
    f32x4 za = zq[0], zb = zq[1], zc = zq[2], zd = zq[3];
    const f32x4* wq = (const f32x4*)(w1t + jj * 16);
    f32x4 wa = wq[0], wb = wq[1], wc = wq[2], wd = wq[3];
    f32x4 me = *(const f32x4*)(meta + jj * 4);
    f32x4 dz4 = zi0 * za + zi1 * zb + zi2 * zc + zi3 * zd;
    float dz = dz4[0] + dz4[1] + dz4[2] + dz4[3];
    f32x4 dw4 = zi0 * wa + zi1 * wb + zi2 * wc + zi3 * wd;
    float dw = dw4[0] + dw4[1] + dw4[2] + dw4[3];
    accq += exp2f(-LOG2E * (sqi + me[0] - 2.f * dz));
    accp += fmaxf(dw + me[1], 0.f) * me[2];
  }
  atomicAdd(&qacc[i], accq);
  atomicAdd(&piacc[i], accp);
}

// ------- K3: dvec_i = sigmoid(piacc_i + b2) / qacc_i --------------------------
__global__ __launch_bounds__(256) void dvec_kernel(
    const float* __restrict__ qacc, const float* __restrict__ piacc,
    const float* __restrict__ b2p, float* __restrict__ dvec)
{
  int i = blockIdx.x * 256 + threadIdx.x;
  float pi = 1.f / (1.f + exp2f(-LOG2E * (piacc[i] + b2p[0])));
  dvec[i] = pi / qacc[i];
}

// ------- K4: W[i][j] = bf16(exp(-d2)*dvec[j]) — pure streaming, no reductions.
//         thread owns 2 adjacent j (regs); loops 64 i from LDS broadcast.
__global__ __launch_bounds__(256) void wmat_kernel(
    const float* __restrict__ z, const float* __restrict__ sq,
    const float* __restrict__ dvec, __hip_bfloat16* __restrict__ W)
{
  __shared__ float zil[64 * 16];    // 4 KB
  __shared__ float sqil[64];
  int tid = threadIdx.x;
  int it = blockIdx.x >> 3, jc = blockIdx.x & 7;
  int i0 = it * 64, j0 = jc * 512;
  ((f32x4*)zil)[tid] = *(const f32x4*)(z + (size_t)i0 * 16 + tid * 4);
  if (tid < 64) sqil[tid] = sq[i0 + tid];
  __syncthreads();
  int j = j0 + tid * 2;
  const f32x4* zjq = (const f32x4*)(z + (size_t)j * 16);
  f32x4 u0 = zjq[0], u1 = zjq[1], u2 = zjq[2], u3 = zjq[3];
  f32x4 v0 = zjq[4], v1 = zjq[5], v2 = zjq[6], v3 = zjq[7];
  float sq0 = sq[j], sq1 = sq[j + 1];
  float dv0 = dvec[j], dv1 = dvec[j + 1];
  for (int ii = 0; ii < 64; ++ii) {
    const f32x4* zq = (const f32x4*)(zil + ii * 16);
    f32x4 a = zq[0], b = zq[1], c = zq[2], d = zq[3];
    f32x4 t0 = a * u0 + b * u1 + c * u2 + d * u3;
    f32x4 t1 = a * v0 + b * v1 + c * v2 + d * v3;
    float dz0 = t0[0] + t0[1] + t0[2] + t0[3];
    float dz1 = t1[0] + t1[1] + t1[2] + t1[3];
    float sqi = sqil[ii];
    float w0 = exp2f(-LOG2E * (sqi + sq0 - 2.f * dz0)) * dv0;
    float w1v = exp2f(-LOG2E * (sqi + sq1 - 2.f * dz1)) * dv1;
    __hip_bfloat162 pk;
    pk.x = __float2bfloat16(w0);
    pk.y = __float2bfloat16(w1v);
    *(__hip_bfloat162*)(W + (size_t)(i0 + ii) * N4096 + j) = pk;
  }
}

// ------- K5: D row-sum of bf16 W (wave/row) -> rowscale + diag-fold -----------
__global__ __launch_bounds__(256) void rsdiag_kernel(
    __hip_bfloat16* __restrict__ W, const float* __restrict__ dvec,
    const float* __restrict__ dtp, float* __restrict__ rowscale)
{
  int tid = threadIdx.x;
  int wv = tid >> 6, lane = tid & 63;
  int row = blockIdx.x * 4 + wv;
  const uint4* p = (const uint4*)(W + (size_t)row * N4096);
  float s = 0.f;
#pragma unroll
  for (int k = 0; k < 8; ++k) {
    uint4 u = p[lane + k * 64];
#pragma unroll
    for (int c = 0; c < 4; ++c) {
      unsigned w = (&u.x)[c];
      union { unsigned u32; float f; } lo, hi;
      lo.u32 = w << 16;
      hi.u32 = w & 0xFFFF0000u;
      s += lo.f + hi.f;
    }
  }
#pragma unroll
  for (int o = 32; o; o >>= 1) s += __shfl_xor(s, o, 64);
  if (lane == 0) {
    float dtv = dtp[0];
    float Dp = s + 1e-5f;
    rowscale[row] = 4.f * dtv / Dp;
    W[(size_t)row * N4096 + row] =
        __float2bfloat16(dvec[row] + (1.f - dtv) * Dp / (4.f * dtv));
  }
}

// ---------------- K6: out = rowscale[i] * (W' @ XFT^T) ------------------------
// FROZEN round-2 schedule: 256x256 tile, BK=64, 8 waves (2Mx4N), counted
// vmcnt(6), raw s_barrier, setprio, XOR-swizzled LDS (both sides), diag-fold.
__global__ __launch_bounds__(512, 2) void gemm8_kernel(
    const __hip_bfloat16* __restrict__ Wm, const __hip_bfloat16* __restrict__ BT,
    const float* __restrict__ rowscale, float* __restrict__ out)
{
  extern __shared__ __bf16 S[];   // [2 bufs][A 16384 | B 16384] = 128 KB
  const int b0 = blockIdx.x;
  const int swz = (b0 & 7) * 32 + (b0 >> 3);   // 256 % 8 == 0: bijective
  const int tm = swz & 15, tn = swz >> 4;
  const int tid = threadIdx.x;
  const int lane = tid & 63;
  const int wv = tid >> 6;
  const int wr = wv >> 2, wc = wv & 3;         // 2 x 4 waves
  const int g = lane >> 4, rr = lane & 15;

  const int srow = tid >> 3;                   // 0..63 within a 64-row unit
  const int lslot = tid & 7;                   // linear LDS slot (8 bf16 each)

  const __hip_bfloat16* Abase = Wm + (size_t)(tm * 256) * N4096;
  const __hip_bfloat16* Bbase = BT + (size_t)(tn * 256) * N4096;

  auto stageA = [&](int tk, int R0) {
    int r = R0 + srow;
    int gc = lslot ^ (r & 7);                  // pre-swizzled global source
    gl_lds16(Abase + (size_t)r * N4096 + tk * 64 + gc * 8,
             S + (size_t)(tk & 1) * 32768 + r * 64 + lslot * 8);
  };
  auto stageB = [&](int tk, int R0) {
    int r = R0 + srow;
    int gc = lslot ^ (r & 7);
    gl_lds16(Bbase + (size_t)r * N4096 + tk * 64 + gc * 8,
             S + (size_t)(tk & 1) * 32768 + 16384 + r * 64 + lslot * 8);
  };

  f32x4 acc[8][4];
#pragma unroll
  for (int i = 0; i < 8; ++i)
#pragma unroll
    for (int j = 0; j < 4; ++j) acc[i][j] = (f32x4){0.f, 0.f, 0.f, 0.f};

  // Prologue: tile0 full (8 units), tile1 partial (6 units, steady-state order)
  stageA(0, 0); stageA(0, 64); stageA(0, 128); stageA(0, 192);
  stageB(0, 0); stageB(0, 64); stageB(0, 128); stageB(0, 192);
  stageB(1, 0); stageB(1, 64); stageB(1, 128); stageB(1, 192);
  stageA(1, 0); stageA(1, 128);
  asm volatile("s_waitcnt vmcnt(6)" ::: "memory");
  bar();

  for (int t = 0; t < NT; ++t) {
    const __bf16* sAb = S + (size_t)(t & 1) * 32768;
    const __bf16* sBb = sAb + 16384;
    bf16x8 bfrag[4][2];

#define APHASE(q)                                                              \
    {                                                                          \
      bf16x8 af[2][2];                                                         \
      _Pragma("unroll")                                                        \
      for (int mi2 = 0; mi2 < 2; ++mi2) {                                      \
        _Pragma("unroll")                                                      \
        for (int kh = 0; kh < 2; ++kh) {                                       \
          int row_ = wr * 128 + ((q) * 2 + mi2) * 16 + rr;                     \
          int slot_ = ((kh << 2) | g) ^ (rr & 7);                              \
          af[mi2][kh] = *(const bf16x8*)(sAb + row_ * 64 + slot_ * 8);         \
        }                                                                      \
      }                                                                        \
      bar();                                                                   \
      __builtin_amdgcn_s_setprio(1);                                          \
      _Pragma("unroll")                                                        \
      for (int kh = 0; kh < 2; ++kh)                                           \
        _Pragma("unroll")                                                      \
        for (int mi2 = 0; mi2 < 2; ++mi2)                                      \
          _Pragma("unroll")                                                    \
          for (int ni = 0; ni < 4; ++ni)                                       \
            acc[(q) * 2 + mi2][ni] = __builtin_amdgcn_mfma_f32_16x16x32_bf16(  \
                af[mi2][kh], bfrag[ni][kh], acc[(q) * 2 + mi2][ni], 0, 0, 0);  \
      __builtin_amdgcn_s_setprio(0);                                          \
    }

    // ---- phase 0: stage tile t+1's last two A units; read B + A-quadrant 0
    if (t + 1 < NT) { stageA(t + 1, 64); stageA(t + 1, 192); }
#pragma unroll
    for (int ni = 0; ni < 4; ++ni)
#pragma unroll
      for (int kh = 0; kh < 2; ++kh) {
        int row_ = wc * 64 + ni * 16 + rr;
        int slot_ = ((kh << 2) | g) ^ (rr & 7);
        bfrag[ni][kh] = *(const bf16x8*)(sBb + row_ * 64 + slot_ * 8);
      }
    APHASE(0);
    bar();
    // ---- phase 1: B of tile t is dead -> stage tile t+2's B half 0
    if (t + 2 < NT) { stageB(t + 2, 0); stageB(t + 2, 64); }
    APHASE(1);
    bar();
    // ---- phase 2: stage tile t+2's B half 1
    if (t + 2 < NT) { stageB(t + 2, 128); stageB(t + 2, 192); }
    APHASE(2);
    bar();
    // ---- phase 3: A units 0,128 of tile t dead after quadrants 0-1 -> stage
    if (t + 2 < NT) { stageA(t + 2, 0); stageA(t + 2, 128); }
    APHASE(3);
    // ---- tile boundary: counted wait (tile t+1 staged; t+2's 6 stay in flight)
    if (t + 2 < NT)      { asm volatile("s_waitcnt vmcnt(6)" ::: "memory"); }
    else if (t + 1 < NT) { asm volatile("s_waitcnt vmcnt(0)" ::: "memory"); }
    bar();
#undef APHASE
  }

#pragma unroll
  for (int mi = 0; mi < 8; ++mi) {
#pragma unroll
    for (int r4 = 0; r4 < 4; ++r4) {
      int row = tm * 256 + wr * 128 + mi * 16 + g * 4 + r4;
      float rs = rowscale[row];
      float* orow = out + (size_t)row * N4096;
#pragma unroll
      for (int ni = 0; ni < 4; ++ni) {
        int col = tn * 256 + wc * 64 + ni * 16 + rr;
        orow[col] = rs * acc[mi][ni][r4];
      }
    }
  }
}

extern "C" void kernel_launch(void* const* d_in, const int* in_sizes, int n_in,
                              void* d_out, int out_size, void* d_ws, size_t ws_size,
                              hipStream_t stream) {
  const float* x      = (const float*)d_in[0];
  const float* proj_w = (const float*)d_in[1];
  const float* proj_b = (const float*)d_in[2];
  const float* pi_w1  = (const float*)d_in[3];
  const float* pi_b1  = (const float*)d_in[4];
  const float* pi_w2  = (const float*)d_in[5];
  const float* pi_b2  = (const float*)d_in[6];
  const float* dt     = (const float*)d_in[7];
  float* out = (float*)d_out;

  char* ws = (char*)d_ws;
  const size_t MB = 1024 * 1024;
  __hip_bfloat16* W   = (__hip_bfloat16*)(ws);               // 32 MB
  __hip_bfloat16* XFT = (__hip_bfloat16*)(ws + 32 * MB);     // 32 MB
  float* z        = (float*)(ws + 64 * MB);                  // 256 KB
  float* sq       = (float*)(ws + 64 * MB + 256 * 1024);     // 16 KB
  float* qacc     = (float*)(ws + 64 * MB + 272 * 1024);     // 16 KB
  float* piacc    = (float*)(ws + 64 * MB + 288 * 1024);     // 16 KB
  float* dvec     = (float*)(ws + 64 * MB + 304 * 1024);     // 16 KB
  float* rowscale = (float*)(ws + 64 * MB + 320 * 1024);     // 16 KB

  (void)hipFuncSetAttribute((const void*)gemm8_kernel,
                            hipFuncAttributeMaxDynamicSharedMemorySize, 131072);

  xpass_kernel<<<4608, 256, 0, stream>>>(x, proj_w, proj_b, z, sq,
                                         qacc, piacc, XFT);
  qpi_kernel<<<512, 256, 0, stream>>>(z, sq, pi_w1, pi_b1, pi_w2, qacc, piacc);
  dvec_kernel<<<16, 256, 0, stream>>>(qacc, piacc, pi_b2, dvec);
  wmat_kernel<<<512, 256, 0, stream>>>(z, sq, dvec, W);
  rsdiag_kernel<<<1024, 256, 0, stream>>>(W, dvec, dt, rowscale);
  gemm8_kernel<<<256, 512, 131072, stream>>>(W, XFT, rowscale, out);
}